// Round 2
// baseline (240.803 us; speedup 1.0000x reference)
//
#include <hip/hip_runtime.h>

// Problem constants
#define LQ   2048
#define BQ   2
#define HID  1024
#define NH   16
#define DH   64
#define SCALE 0.125f
#define L2E  1.44269504088896f
#define C1   0.18033688011f     // SCALE * log2(e)
#define EXPOFF 23.0831206542f   // 16 * log2(e); fixed softmax max M=16

using short8  = __attribute__((ext_vector_type(8))) short;
using ushort8 = __attribute__((ext_vector_type(8))) unsigned short;
using f32x4   = __attribute__((ext_vector_type(4))) float;
typedef unsigned short u16;
typedef __attribute__((ext_vector_type(2))) __bf16 bf16x2;

__device__ inline u16 f2bf(float x) {
    unsigned int u = __float_as_uint(x);
    u = (u + 0x7fffu + ((u >> 16) & 1u)) >> 16;   // RNE
    return (u16)u;
}

#if defined(__has_builtin)
#if __has_builtin(__builtin_amdgcn_cvt_pk_bf16_f32)
#define HAVE_PKBF 1
#endif
#if __has_builtin(__builtin_amdgcn_exp2f)
#define HAVE_EXP2 1
#endif
#endif

__device__ inline unsigned int pkbf(float a, float b) {
#ifdef HAVE_PKBF
    bf16x2 r = __builtin_amdgcn_cvt_pk_bf16_f32(a, b);
    return __builtin_bit_cast(unsigned int, r);
#else
    return (unsigned int)f2bf(a) | ((unsigned int)f2bf(b) << 16);
#endif
}

__device__ inline float fexp2(float x) {
#ifdef HAVE_EXP2
    return __builtin_amdgcn_exp2f(x);
#else
    return exp2f(x);
#endif
}

// async global->LDS, 16B per lane; LDS dest = wave-uniform base + lane*16
__device__ inline void gl_lds16(const void* g, void* l) {
    __builtin_amdgcn_global_load_lds(
        (const __attribute__((address_space(1))) void*)g,
        (__attribute__((address_space(3))) void*)l, 16, 0, 0);
}

// ---------------------------------------------------------------------------
// castw: cast 7 tensors fp32->bf16 (y=0..6) + mask decode (y==7, x==0).
// ---------------------------------------------------------------------------
struct CastArgs {
    const float* s[7];
    u16* d[7];
    int n[7];
    const unsigned char* mraw;
    int* mout;
    int mn;
};

__global__ __launch_bounds__(256) void castw(CastArgs a) {
    const int y = blockIdx.y;
    const int t = threadIdx.x;
    if (y == 7) {
        if (blockIdx.x != 0) return;
        __shared__ int cnt;
        if (t == 0) cnt = 0;
        __syncthreads();
        int local = 0;
        for (int i = t; i < a.mn; i += 256)
            if ((i & 3) && a.mraw[i]) local++;
        atomicAdd(&cnt, local);
        __syncthreads();
        bool isInt32 = (cnt == 0);
        const int* mi = (const int*)a.mraw;
        for (int i = t; i < a.mn; i += 256)
            a.mout[i] = isInt32 ? mi[i] : (int)a.mraw[i];
        return;
    }
    const float* s = a.s[y];
    u16* d = a.d[y];
    const int n4 = a.n[y] >> 2;
    for (int i = blockIdx.x * 256 + t; i < n4; i += gridDim.x * 256) {
        float4 v = *(const float4*)(s + (size_t)i * 4);
        uint2 p;
        p.x = pkbf(v.x, v.y);
        p.y = pkbf(v.z, v.w);
        *(uint2*)(d + (size_t)i * 4) = p;
    }
}

// ---------------------------------------------------------------------------
// Batched QKV MFMA bf16 GEMM, BK=64, tile 128x128, 256 thr.
// DOUBLE-BUFFERED LDS + single barrier per K-step (2-phase prefetch).
// LDS [2][128][64] unpadded, XOR swizzle: 16B chunk c of row r at slot c^(r&7).
// z=0,1: write bf16 [bh][l][d]. z=2: write bf16 V^T [bh][d][l].
// ---------------------------------------------------------------------------
struct QkvArgs {
    const u16* A[3];
    const u16* W[3];
    const float* bias[3];
    u16* out[3];
};

__global__ __launch_bounds__(256) void gemm_qkv(QkvArgs ga) {
    __shared__ u16 As[2][128][64];
    __shared__ u16 Bs[2][128][64];

    const int z = blockIdx.z;
    const u16* A = ga.A[z];
    const u16* W = ga.W[z];
    const float* bias = ga.bias[z];
    u16* outp = ga.out[z];

    const int t = threadIdx.x;
    const int m0 = blockIdx.x * 128;
    const int n0 = blockIdx.y * 128;
    const int lane = t & 63;
    const int lane15 = lane & 15;
    const int quad = lane >> 4;
    const int w = t >> 6;
    const int wm = (w >> 1) * 64;
    const int wn = (w & 1) * 64;

    const int lrow = lane >> 3;                     // 0..7
    const int ch = (lane & 7) ^ ((lane >> 3) & 7);  // source chunk
    const u16* aS = A + (size_t)(m0 + 32 * w + lrow) * HID + 8 * ch;
    const u16* bS = W + (size_t)(n0 + 32 * w + lrow) * HID + 8 * ch;

    const int s0 = (quad ^ (lane15 & 7)) * 8;
    const int s1 = ((4 + quad) ^ (lane15 & 7)) * 8;

    f32x4 acc[4][4];
#pragma unroll
    for (int i = 0; i < 4; i++)
#pragma unroll
        for (int j = 0; j < 4; j++) acc[i][j] = (f32x4){0,0,0,0};

    // prologue: stage tile 0 into buffer 0
#pragma unroll
    for (int i = 0; i < 4; i++) {
        gl_lds16(aS + (size_t)(8 * i) * HID, &As[0][32 * w + 8 * i][0]);
        gl_lds16(bS + (size_t)(8 * i) * HID, &Bs[0][32 * w + 8 * i][0]);
    }
    __syncthreads();

    int p = 0;
    for (int k0 = 0; k0 < HID; k0 += 64) {
        short8 af0[4], af1[4], bf0[4], bf1[4];
#pragma unroll
        for (int i = 0; i < 4; i++) {
            const u16* ar = &As[p][wm + i * 16 + lane15][0];
            const u16* br = &Bs[p][wn + i * 16 + lane15][0];
            af0[i] = *(const short8*)(ar + s0);
            af1[i] = *(const short8*)(ar + s1);
            bf0[i] = *(const short8*)(br + s0);
            bf1[i] = *(const short8*)(br + s1);
        }
        if (k0 + 64 < HID) {
#pragma unroll
            for (int i = 0; i < 4; i++) {
                gl_lds16(aS + (size_t)(8 * i) * HID + (k0 + 64), &As[p ^ 1][32 * w + 8 * i][0]);
                gl_lds16(bS + (size_t)(8 * i) * HID + (k0 + 64), &Bs[p ^ 1][32 * w + 8 * i][0]);
            }
        }
#pragma unroll
        for (int mi = 0; mi < 4; mi++)
#pragma unroll
            for (int ni = 0; ni < 4; ni++) {
                acc[mi][ni] = __builtin_amdgcn_mfma_f32_16x16x32_bf16(af0[mi], bf0[ni], acc[mi][ni], 0, 0, 0);
                acc[mi][ni] = __builtin_amdgcn_mfma_f32_16x16x32_bf16(af1[mi], bf1[ni], acc[mi][ni], 0, 0, 0);
            }
        __syncthreads();
        p ^= 1;
    }

#pragma unroll
    for (int mi = 0; mi < 4; mi++) {
#pragma unroll
        for (int ni = 0; ni < 4; ni++) {
            const int n = n0 + wn + ni * 16 + lane15;
            const float bv = bias[n];
            const int h = n >> 6, d = n & 63;
#pragma unroll
            for (int r = 0; r < 4; r++) {
                const int m = m0 + wm + mi * 16 + quad * 4 + r;
                const float c = acc[mi][ni][r] + bv;
                const int b = m & 1, l = m >> 1;
                if (z < 2) {
                    outp[(((size_t)(b * NH + h)) * LQ + l) * DH + d] = f2bf(c);
                } else {
                    outp[(((size_t)(b * NH + h)) * DH + d) * LQ + l] = f2bf(c);
                }
            }
        }
    }
}

// ---------------------------------------------------------------------------
// FC GEMM (fp32 out), 128x64 tile, BK=64, double-buffered 2-phase.
// ---------------------------------------------------------------------------
__global__ __launch_bounds__(256) void gemm_fc(const u16* __restrict__ A,
                                               const u16* __restrict__ W,
                                               const float* __restrict__ bias,
                                               float* __restrict__ outp) {
    __shared__ u16 As[2][128][64];
    __shared__ u16 Bs[2][64][64];

    const int t = threadIdx.x;
    const int m0 = blockIdx.x * 128;
    const int n0 = blockIdx.y * 64;
    const int lane = t & 63;
    const int lane15 = lane & 15;
    const int quad = lane >> 4;
    const int w = t >> 6;
    const int wm = (w >> 1) * 64;
    const int wn = (w & 1) * 32;

    const int lrow = lane >> 3;
    const int ch = (lane & 7) ^ ((lane >> 3) & 7);
    const u16* aS = A + (size_t)(m0 + 32 * w + lrow) * HID + 8 * ch;
    const u16* bS = W + (size_t)(n0 + 16 * w + lrow) * HID + 8 * ch;

    const int s0 = (quad ^ (lane15 & 7)) * 8;
    const int s1 = ((4 + quad) ^ (lane15 & 7)) * 8;

    f32x4 acc[4][2];
#pragma unroll
    for (int i = 0; i < 4; i++)
#pragma unroll
        for (int j = 0; j < 2; j++) acc[i][j] = (f32x4){0,0,0,0};

#pragma unroll
    for (int i = 0; i < 4; i++)
        gl_lds16(aS + (size_t)(8 * i) * HID, &As[0][32 * w + 8 * i][0]);
#pragma unroll
    for (int i = 0; i < 2; i++)
        gl_lds16(bS + (size_t)(8 * i) * HID, &Bs[0][16 * w + 8 * i][0]);
    __syncthreads();

    int p = 0;
    for (int k0 = 0; k0 < HID; k0 += 64) {
        short8 af0[4], af1[4], bf0[2], bf1[2];
#pragma unroll
        for (int i = 0; i < 4; i++) {
            const u16* ar = &As[p][wm + i * 16 + lane15][0];
            af0[i] = *(const short8*)(ar + s0);
            af1[i] = *(const short8*)(ar + s1);
        }
#pragma unroll
        for (int j = 0; j < 2; j++) {
            const u16* br = &Bs[p][wn + j * 16 + lane15][0];
            bf0[j] = *(const short8*)(br + s0);
            bf1[j] = *(const short8*)(br + s1);
        }
        if (k0 + 64 < HID) {
#pragma unroll
            for (int i = 0; i < 4; i++)
                gl_lds16(aS + (size_t)(8 * i) * HID + (k0 + 64), &As[p ^ 1][32 * w + 8 * i][0]);
#pragma unroll
            for (int i = 0; i < 2; i++)
                gl_lds16(bS + (size_t)(8 * i) * HID + (k0 + 64), &Bs[p ^ 1][16 * w + 8 * i][0]);
        }
#pragma unroll
        for (int mi = 0; mi < 4; mi++)
#pragma unroll
            for (int ni = 0; ni < 2; ni++) {
                acc[mi][ni] = __builtin_amdgcn_mfma_f32_16x16x32_bf16(af0[mi], bf0[ni], acc[mi][ni], 0, 0, 0);
                acc[mi][ni] = __builtin_amdgcn_mfma_f32_16x16x32_bf16(af1[mi], bf1[ni], acc[mi][ni], 0, 0, 0);
            }
        __syncthreads();
        p ^= 1;
    }

#pragma unroll
    for (int mi = 0; mi < 4; mi++) {
#pragma unroll
        for (int ni = 0; ni < 2; ni++) {
            const int n = n0 + wn + ni * 16 + lane15;
            const float bv = bias[n];
#pragma unroll
            for (int r = 0; r < 4; r++) {
                const int m = m0 + wm + mi * 16 + quad * 4 + r;
                outp[(size_t)m * HID + n] = acc[mi][ni][r] + bv;
            }
        }
    }
}

// ---------------------------------------------------------------------------
// MFMA bf16 flash attention v3: 64-key chunks, DOUBLE-BUFFERED K/V LDS,
// single barrier per chunk, prefetch chunk c+1 during compute of chunk c.
// Contiguous chunk range [c_lo, c_hi] (finer 64-key skip granularity).
// Full mask row hoisted to LDS once per block. Pre-scaled quadratic bias
// (d' = d*sqrt(-nb2)) saves one VALU op per element.
// ---------------------------------------------------------------------------
#define PSTR 72

__global__ __launch_bounds__(512) void attn_kernel(const u16* __restrict__ Qg,
                                                   const u16* __restrict__ Kg,
                                                   const u16* __restrict__ Vtg,
                                                   const int* __restrict__ maskI,
                                                   const float* __restrict__ tao,
                                                   u16* __restrict__ Xa) {
    __shared__ u16 Ks[2][64][64];   // [buf][key][d], chunk c of row r at slot c^(r&7)
    __shared__ u16 Vt[2][64][64];   // [buf][d][key], same swizzle on key-chunks
    __shared__ u16 PT[128][PSTR];   // wave-private rows
    __shared__ float smaskF[LQ];    // full mask row, loaded once

    const int bh = blockIdx.x;
    const int q0 = blockIdx.y * 128;
    const int b = bh >> 4;
    const int h = bh & 15;
    const int t = threadIdx.x;
    const int w = t >> 6;            // wave 0..7
    const int lane = t & 63;
    const int lane15 = lane & 15;
    const int quad = lane >> 4;

    const u16* Kbase = Kg + (size_t)bh * LQ * DH;
    const u16* Vtbase = Vtg + (size_t)bh * DH * LQ;
    const int* mrow = maskI + b * LQ;

    const float tv = tao[h];
    const float t2 = tv * tv;
    const float nb = -0.5f / (t2 * t2);
    const float nb2 = nb * L2E;             // negative
    const float sqn = sqrtf(-nb2);
    const float R = sqrtf(-40.0f / nb2) + 1.0f;   // conservative (superset)

    // contiguous chunk range
    int c_lo = (int)floorf(((float)q0 - R) * (1.0f / 64.0f));
    int c_hi = (int)floorf(((float)(q0 + 127) + R) * (1.0f / 64.0f));
    if (c_lo < 0) c_lo = 0;
    if (c_hi > (LQ / 64 - 1)) c_hi = LQ / 64 - 1;
    if (c_hi < c_lo) c_hi = c_lo;

    // staging source pointers (per-chunk offset added in loop)
    const int lr = lane >> 3;        // 0..7
    const int lc = lane & 7;
    const int sch = lc ^ lr;         // XOR-swizzled source 16B chunk
    const u16* kS = Kbase + (size_t)(8 * w + lr) * DH + 8 * sch;
    const u16* vS = Vtbase + (size_t)(8 * w + lr) * LQ + 8 * sch;

    // prologue: start first chunk's loads, then mask init, then barrier
    gl_lds16(kS + (size_t)(64 * c_lo) * DH, &Ks[0][8 * w][0]);
    gl_lds16(vS + 64 * c_lo, &Vt[0][8 * w][0]);
    for (int i = t; i < LQ; i += 512)
        smaskF[i] = mrow[i] ? -3.0e38f : -EXPOFF;

    const int qrow = q0 + w * 16 + lane15;
    short8 qB0, qB1;
    {
        const u16* qp_ = Qg + ((size_t)bh * LQ + qrow) * DH + quad * 8;
        qB0 = *(const short8*)(qp_);
        qB1 = *(const short8*)(qp_ + 32);
    }

    const int s0 = (quad ^ (lane15 & 7)) * 8;
    const int s1 = ((4 + quad) ^ (lane15 & 7)) * 8;

    f32x4 O[4];
#pragma unroll
    for (int mt = 0; mt < 4; mt++) O[mt] = (f32x4){0,0,0,0};
    float l_ = 0.0f;

    const float ebase0 = (float)(qrow - quad * 4);
    const int prow = w * 16 + lane15;

    __syncthreads();

    int p = 0;
    for (int c = c_lo; c <= c_hi; ++c) {
        // prefetch next chunk into other buffer (no wait; drains at barrier)
        if (c < c_hi) {
            gl_lds16(kS + (size_t)(64 * (c + 1)) * DH, &Ks[p ^ 1][8 * w][0]);
            gl_lds16(vS + 64 * (c + 1), &Vt[p ^ 1][8 * w][0]);
        }

        // QK^T: S[kt] = K[16 keys] x Q[16 q] over D=64
        f32x4 S[4];
#pragma unroll
        for (int kt = 0; kt < 4; kt++) {
            const u16* kr = &Ks[p][kt * 16 + lane15][0];
            const short8 ka = *(const short8*)(kr + s0);
            const short8 kb = *(const short8*)(kr + s1);
            S[kt] = __builtin_amdgcn_mfma_f32_16x16x32_bf16(ka, qB0, (f32x4){0,0,0,0}, 0, 0, 0);
            S[kt] = __builtin_amdgcn_mfma_f32_16x16x32_bf16(kb, qB1, S[kt], 0, 0, 0);
        }

        // softmax (fixed max): p = exp2(S*C1 - d'^2 + mask)
        const float eb = (ebase0 - (float)(64 * c)) * sqn;
        float lacc = 0.0f;
#pragma unroll
        for (int kt = 0; kt < 4; kt++) {
            const float4 sm4 = *(const float4*)&smaskF[64 * c + kt * 16 + quad * 4];
            float pr[4];
#pragma unroll
            for (int r = 0; r < 4; r++) {
                const float dp = eb - (float)(kt * 16 + r) * sqn;  // hoisted consts
                const float tb = fmaf(-dp, dp, ((const float*)&sm4)[r]);
                pr[r] = fexp2(fmaf(S[kt][r], C1, tb));
                lacc += pr[r];
            }
            uint2 pk2;
            pk2.x = pkbf(pr[0], pr[1]);
            pk2.y = pkbf(pr[2], pr[3]);
            *(uint2*)&PT[prow][kt * 16 + quad * 4] = pk2;
        }
        l_ += lacc;

        // PV: O += V^T[d][64 keys] x P[64 keys][16 q]
        const short8 pB0 = *(const short8*)&PT[prow][quad * 8];
        const short8 pB1 = *(const short8*)&PT[prow][32 + quad * 8];
#pragma unroll
        for (int mt = 0; mt < 4; mt++) {
            const u16* vr = &Vt[p][mt * 16 + lane15][0];
            const short8 va = *(const short8*)(vr + s0);
            const short8 vb = *(const short8*)(vr + s1);
            O[mt] = __builtin_amdgcn_mfma_f32_16x16x32_bf16(va, pB0, O[mt], 0, 0, 0);
            O[mt] = __builtin_amdgcn_mfma_f32_16x16x32_bf16(vb, pB1, O[mt], 0, 0, 0);
        }

        __syncthreads();
        p ^= 1;
    }

    l_ += __shfl_xor(l_, 16, 64);
    l_ += __shfl_xor(l_, 32, 64);

    {
        const float inv = 1.0f / l_;
        u16* dst = Xa + ((size_t)qrow * BQ + b) * HID + h * DH;
#pragma unroll
        for (int mt = 0; mt < 4; mt++) {
            uint2 pk2;
            pk2.x = pkbf(O[mt][0] * inv, O[mt][1] * inv);
            pk2.y = pkbf(O[mt][2] * inv, O[mt][3] * inv);
            *(uint2*)(dst + mt * 16 + quad * 4) = pk2;
        }
    }
}

// ---------------------------------------------------------------------------
extern "C" void kernel_launch(void* const* d_in, const int* in_sizes, int n_in,
                              void* d_out, int out_size, void* d_ws, size_t ws_size,
                              hipStream_t stream) {
    const float* q    = (const float*)d_in[0];
    const float* k    = (const float*)d_in[1];
    const float* v    = (const float*)d_in[2];
    const void*  mask = d_in[3];
    const float* wq   = (const float*)d_in[4];
    const float* wk   = (const float*)d_in[5];
    const float* wv   = (const float*)d_in[6];
    const float* wfc  = (const float*)d_in[7];
    const float* bq   = (const float*)d_in[8];
    const float* bk   = (const float*)d_in[9];
    const float* bv   = (const float*)d_in[10];
    const float* bfc  = (const float*)d_in[11];
    const float* tao  = (const float*)d_in[12];

    const size_t NE = (size_t)LQ * BQ * HID;  // 4,194,304
    const size_t NW = (size_t)HID * HID;      // 1,048,576
    u16* base = (u16*)d_ws;
    u16* Qp    = base;            // [bh][l][d]
    u16* Kp    = base + NE;       // [bh][l][d]
    u16* Vtp   = base + 2 * NE;   // [bh][d][l]
    u16* Xa    = base + 3 * NE;
    u16* qbf   = base + 4 * NE;
    u16* kbf   = base + 5 * NE;
    u16* vbf   = base + 6 * NE;
    u16* wqbf  = base + 7 * NE;
    u16* wkbf  = wqbf + NW;
    u16* wvbf  = wkbf + NW;
    u16* wfcbf = wvbf + NW;
    int* maskI = (int*)(wfcbf + NW);

    CastArgs ca;
    ca.s[0] = q;   ca.d[0] = qbf;   ca.n[0] = (int)NE;
    ca.s[1] = k;   ca.d[1] = kbf;   ca.n[1] = (int)NE;
    ca.s[2] = v;   ca.d[2] = vbf;   ca.n[2] = (int)NE;
    ca.s[3] = wq;  ca.d[3] = wqbf;  ca.n[3] = (int)NW;
    ca.s[4] = wk;  ca.d[4] = wkbf;  ca.n[4] = (int)NW;
    ca.s[5] = wv;  ca.d[5] = wvbf;  ca.n[5] = (int)NW;
    ca.s[6] = wfc; ca.d[6] = wfcbf; ca.n[6] = (int)NW;
    ca.mraw = (const unsigned char*)mask;
    ca.mout = maskI;
    ca.mn = BQ * LQ;
    castw<<<dim3(256, 8), 256, 0, stream>>>(ca);

    QkvArgs ga;
    ga.A[0] = qbf;  ga.W[0] = wqbf;  ga.bias[0] = bq;  ga.out[0] = Qp;
    ga.A[1] = kbf;  ga.W[1] = wkbf;  ga.bias[1] = bk;  ga.out[1] = Kp;
    ga.A[2] = vbf;  ga.W[2] = wvbf;  ga.bias[2] = bv;  ga.out[2] = Vtp;
    gemm_qkv<<<dim3(32, 8, 3), 256, 0, stream>>>(ga);

    attn_kernel<<<dim3(32, 16), 512, 0, stream>>>(Qp, Kp, Vtp, maskI, tao, Xa);

    gemm_fc<<<dim3(32, 16), 256, 0, stream>>>(Xa, wfcbf, bfc, (float*)d_out);
}

// Round 3
// 236.533 us; speedup vs baseline: 1.0181x; 1.0181x over previous
//
#include <hip/hip_runtime.h>

// Problem constants
#define LQ   2048
#define BQ   2
#define HID  1024
#define NH   16
#define DH   64
#define SCALE 0.125f
#define L2E  1.44269504088896f
#define C1   0.18033688011f     // SCALE * log2(e)
#define EXPOFF 23.0831206542f   // 16 * log2(e); fixed softmax max M=16
#define MASKNEG (-1024.0f)      // masked-key additive bias (pre-scale-free, in log2 units after *C1? no: folded directly)

using short8  = __attribute__((ext_vector_type(8))) short;
using ushort8 = __attribute__((ext_vector_type(8))) unsigned short;
using f32x4   = __attribute__((ext_vector_type(4))) float;
typedef unsigned short u16;
typedef __attribute__((ext_vector_type(2))) __bf16 bf16x2;

__device__ inline u16 f2bf(float x) {
    unsigned int u = __float_as_uint(x);
    u = (u + 0x7fffu + ((u >> 16) & 1u)) >> 16;   // RNE
    return (u16)u;
}

#if defined(__has_builtin)
#if __has_builtin(__builtin_amdgcn_cvt_pk_bf16_f32)
#define HAVE_PKBF 1
#endif
#if __has_builtin(__builtin_amdgcn_exp2f)
#define HAVE_EXP2 1
#endif
#endif

__device__ inline unsigned int pkbf(float a, float b) {
#ifdef HAVE_PKBF
    bf16x2 r = __builtin_amdgcn_cvt_pk_bf16_f32(a, b);
    return __builtin_bit_cast(unsigned int, r);
#else
    return (unsigned int)f2bf(a) | ((unsigned int)f2bf(b) << 16);
#endif
}

__device__ inline float fexp2(float x) {
#ifdef HAVE_EXP2
    return __builtin_amdgcn_exp2f(x);
#else
    return exp2f(x);
#endif
}

// async global->LDS, 16B per lane; LDS dest = wave-uniform base + lane*16
__device__ inline void gl_lds16(const void* g, void* l) {
    __builtin_amdgcn_global_load_lds(
        (const __attribute__((address_space(1))) void*)g,
        (__attribute__((address_space(3))) void*)l, 16, 0, 0);
}

// ---------------------------------------------------------------------------
// castw: cast 7 tensors fp32->bf16 (y=0..6) + mask decode (y==7, x==0).
// Mask now emits FLOAT additive bias per key: -EXPOFF (keep) or
// -1024-EXPOFF (masked; exp2 underflows to exactly 0).
// ---------------------------------------------------------------------------
struct CastArgs {
    const float* s[7];
    u16* d[7];
    int n[7];
    const unsigned char* mraw;
    float* mout;
    int mn;
};

__global__ __launch_bounds__(256) void castw(CastArgs a) {
    const int y = blockIdx.y;
    const int t = threadIdx.x;
    if (y == 7) {
        if (blockIdx.x != 0) return;
        __shared__ int cnt;
        if (t == 0) cnt = 0;
        __syncthreads();
        int local = 0;
        for (int i = t; i < a.mn; i += 256)
            if ((i & 3) && a.mraw[i]) local++;
        atomicAdd(&cnt, local);
        __syncthreads();
        bool isInt32 = (cnt == 0);
        const int* mi = (const int*)a.mraw;
        for (int i = t; i < a.mn; i += 256) {
            const bool m = isInt32 ? (mi[i] != 0) : (a.mraw[i] != 0);
            a.mout[i] = m ? (MASKNEG - EXPOFF) : (-EXPOFF);
        }
        return;
    }
    const float* s = a.s[y];
    u16* d = a.d[y];
    const int n4 = a.n[y] >> 2;
    for (int i = blockIdx.x * 256 + t; i < n4; i += gridDim.x * 256) {
        float4 v = *(const float4*)(s + (size_t)i * 4);
        uint2 p;
        p.x = pkbf(v.x, v.y);
        p.y = pkbf(v.z, v.w);
        *(uint2*)(d + (size_t)i * 4) = p;
    }
}

// ---------------------------------------------------------------------------
// Batched QKV MFMA bf16 GEMM, BK=64, tile 128x128, 256 thr.
// DOUBLE-BUFFERED LDS + single barrier per K-step (2-phase prefetch).
// LDS [2][128][64] unpadded, XOR swizzle: 16B chunk c of row r at slot c^(r&7).
// z=0,1: write bf16 [bh][l][d]. z=2: write bf16 V^T [bh][d][l].
// ---------------------------------------------------------------------------
struct QkvArgs {
    const u16* A[3];
    const u16* W[3];
    const float* bias[3];
    u16* out[3];
};

__global__ __launch_bounds__(256) void gemm_qkv(QkvArgs ga) {
    __shared__ u16 As[2][128][64];
    __shared__ u16 Bs[2][128][64];

    const int z = blockIdx.z;
    const u16* A = ga.A[z];
    const u16* W = ga.W[z];
    const float* bias = ga.bias[z];
    u16* outp = ga.out[z];

    const int t = threadIdx.x;
    const int m0 = blockIdx.x * 128;
    const int n0 = blockIdx.y * 128;
    const int lane = t & 63;
    const int lane15 = lane & 15;
    const int quad = lane >> 4;
    const int w = t >> 6;
    const int wm = (w >> 1) * 64;
    const int wn = (w & 1) * 64;

    const int lrow = lane >> 3;                     // 0..7
    const int ch = (lane & 7) ^ ((lane >> 3) & 7);  // source chunk
    const u16* aS = A + (size_t)(m0 + 32 * w + lrow) * HID + 8 * ch;
    const u16* bS = W + (size_t)(n0 + 32 * w + lrow) * HID + 8 * ch;

    const int s0 = (quad ^ (lane15 & 7)) * 8;
    const int s1 = ((4 + quad) ^ (lane15 & 7)) * 8;

    f32x4 acc[4][4];
#pragma unroll
    for (int i = 0; i < 4; i++)
#pragma unroll
        for (int j = 0; j < 4; j++) acc[i][j] = (f32x4){0,0,0,0};

    // prologue: stage tile 0 into buffer 0
#pragma unroll
    for (int i = 0; i < 4; i++) {
        gl_lds16(aS + (size_t)(8 * i) * HID, &As[0][32 * w + 8 * i][0]);
        gl_lds16(bS + (size_t)(8 * i) * HID, &Bs[0][32 * w + 8 * i][0]);
    }
    __syncthreads();

    int p = 0;
    for (int k0 = 0; k0 < HID; k0 += 64) {
        short8 af0[4], af1[4], bf0[4], bf1[4];
#pragma unroll
        for (int i = 0; i < 4; i++) {
            const u16* ar = &As[p][wm + i * 16 + lane15][0];
            const u16* br = &Bs[p][wn + i * 16 + lane15][0];
            af0[i] = *(const short8*)(ar + s0);
            af1[i] = *(const short8*)(ar + s1);
            bf0[i] = *(const short8*)(br + s0);
            bf1[i] = *(const short8*)(br + s1);
        }
        if (k0 + 64 < HID) {
#pragma unroll
            for (int i = 0; i < 4; i++) {
                gl_lds16(aS + (size_t)(8 * i) * HID + (k0 + 64), &As[p ^ 1][32 * w + 8 * i][0]);
                gl_lds16(bS + (size_t)(8 * i) * HID + (k0 + 64), &Bs[p ^ 1][32 * w + 8 * i][0]);
            }
        }
#pragma unroll
        for (int mi = 0; mi < 4; mi++)
#pragma unroll
            for (int ni = 0; ni < 4; ni++) {
                acc[mi][ni] = __builtin_amdgcn_mfma_f32_16x16x32_bf16(af0[mi], bf0[ni], acc[mi][ni], 0, 0, 0);
                acc[mi][ni] = __builtin_amdgcn_mfma_f32_16x16x32_bf16(af1[mi], bf1[ni], acc[mi][ni], 0, 0, 0);
            }
        __syncthreads();
        p ^= 1;
    }

#pragma unroll
    for (int mi = 0; mi < 4; mi++) {
#pragma unroll
        for (int ni = 0; ni < 4; ni++) {
            const int n = n0 + wn + ni * 16 + lane15;
            const float bv = bias[n];
            const int h = n >> 6, d = n & 63;
#pragma unroll
            for (int r = 0; r < 4; r++) {
                const int m = m0 + wm + mi * 16 + quad * 4 + r;
                const float c = acc[mi][ni][r] + bv;
                const int b = m & 1, l = m >> 1;
                if (z < 2) {
                    outp[(((size_t)(b * NH + h)) * LQ + l) * DH + d] = f2bf(c);
                } else {
                    outp[(((size_t)(b * NH + h)) * DH + d) * LQ + l] = f2bf(c);
                }
            }
        }
    }
}

// ---------------------------------------------------------------------------
// FC GEMM (fp32 out), 128x64 tile, BK=64, double-buffered 2-phase.
// ---------------------------------------------------------------------------
__global__ __launch_bounds__(256) void gemm_fc(const u16* __restrict__ A,
                                               const u16* __restrict__ W,
                                               const float* __restrict__ bias,
                                               float* __restrict__ outp) {
    __shared__ u16 As[2][128][64];
    __shared__ u16 Bs[2][64][64];

    const int t = threadIdx.x;
    const int m0 = blockIdx.x * 128;
    const int n0 = blockIdx.y * 64;
    const int lane = t & 63;
    const int lane15 = lane & 15;
    const int quad = lane >> 4;
    const int w = t >> 6;
    const int wm = (w >> 1) * 64;
    const int wn = (w & 1) * 32;

    const int lrow = lane >> 3;
    const int ch = (lane & 7) ^ ((lane >> 3) & 7);
    const u16* aS = A + (size_t)(m0 + 32 * w + lrow) * HID + 8 * ch;
    const u16* bS = W + (size_t)(n0 + 16 * w + lrow) * HID + 8 * ch;

    const int s0 = (quad ^ (lane15 & 7)) * 8;
    const int s1 = ((4 + quad) ^ (lane15 & 7)) * 8;

    f32x4 acc[4][2];
#pragma unroll
    for (int i = 0; i < 4; i++)
#pragma unroll
        for (int j = 0; j < 2; j++) acc[i][j] = (f32x4){0,0,0,0};

#pragma unroll
    for (int i = 0; i < 4; i++)
        gl_lds16(aS + (size_t)(8 * i) * HID, &As[0][32 * w + 8 * i][0]);
#pragma unroll
    for (int i = 0; i < 2; i++)
        gl_lds16(bS + (size_t)(8 * i) * HID, &Bs[0][16 * w + 8 * i][0]);
    __syncthreads();

    int p = 0;
    for (int k0 = 0; k0 < HID; k0 += 64) {
        short8 af0[4], af1[4], bf0[2], bf1[2];
#pragma unroll
        for (int i = 0; i < 4; i++) {
            const u16* ar = &As[p][wm + i * 16 + lane15][0];
            af0[i] = *(const short8*)(ar + s0);
            af1[i] = *(const short8*)(ar + s1);
        }
#pragma unroll
        for (int j = 0; j < 2; j++) {
            const u16* br = &Bs[p][wn + j * 16 + lane15][0];
            bf0[j] = *(const short8*)(br + s0);
            bf1[j] = *(const short8*)(br + s1);
        }
        if (k0 + 64 < HID) {
#pragma unroll
            for (int i = 0; i < 4; i++)
                gl_lds16(aS + (size_t)(8 * i) * HID + (k0 + 64), &As[p ^ 1][32 * w + 8 * i][0]);
#pragma unroll
            for (int i = 0; i < 2; i++)
                gl_lds16(bS + (size_t)(8 * i) * HID + (k0 + 64), &Bs[p ^ 1][16 * w + 8 * i][0]);
        }
#pragma unroll
        for (int mi = 0; mi < 4; mi++)
#pragma unroll
            for (int ni = 0; ni < 2; ni++) {
                acc[mi][ni] = __builtin_amdgcn_mfma_f32_16x16x32_bf16(af0[mi], bf0[ni], acc[mi][ni], 0, 0, 0);
                acc[mi][ni] = __builtin_amdgcn_mfma_f32_16x16x32_bf16(af1[mi], bf1[ni], acc[mi][ni], 0, 0, 0);
            }
        __syncthreads();
        p ^= 1;
    }

#pragma unroll
    for (int mi = 0; mi < 4; mi++) {
#pragma unroll
        for (int ni = 0; ni < 2; ni++) {
            const int n = n0 + wn + ni * 16 + lane15;
            const float bv = bias[n];
#pragma unroll
            for (int r = 0; r < 4; r++) {
                const int m = m0 + wm + mi * 16 + quad * 4 + r;
                outp[(size_t)m * HID + n] = acc[mi][ni][r] + bv;
            }
        }
    }
}

// ---------------------------------------------------------------------------
// MFMA bf16 flash attention v4:
//  - q-tile 64, 256 threads (4 waves), grid 32x32=1024 blocks -> 3 blocks/CU
//    (LDS 41 KB), desynced fine-grained barriers.
//  - 64-key chunks, K/V double-buffered, 1 barrier/chunk, prefetch c+1.
//  - mask bias read from GLOBAL (float, -EXPOFF or -1024-EXPOFF) into regs;
//    no mask LDS, loads issued BEFORE gl_lds prefetch (vmcnt ordering).
//  - row-sum l via MFMA with ones-A on pB0/pB1 (no VALU adds, no shuffles).
// ---------------------------------------------------------------------------
#define PSTR 72

__global__ __launch_bounds__(256, 3) void attn_kernel(const u16* __restrict__ Qg,
                                                      const u16* __restrict__ Kg,
                                                      const u16* __restrict__ Vtg,
                                                      const float* __restrict__ maskF,
                                                      const float* __restrict__ tao,
                                                      u16* __restrict__ Xa) {
    __shared__ u16 Ks[2][64][64];   // [buf][key][d], chunk c of row r at slot c^(r&7)
    __shared__ u16 Vt[2][64][64];   // [buf][d][key], same swizzle
    __shared__ u16 PT[64][PSTR];    // wave-private rows

    const int bh = blockIdx.x;
    const int q0 = blockIdx.y * 64;
    const int b = bh >> 4;
    const int h = bh & 15;
    const int t = threadIdx.x;
    const int w = t >> 6;            // wave 0..3
    const int lane = t & 63;
    const int lane15 = lane & 15;
    const int quad = lane >> 4;

    const u16* Kbase = Kg + (size_t)bh * LQ * DH;
    const u16* Vtbase = Vtg + (size_t)bh * DH * LQ;
    const float* mrow = maskF + b * LQ;

    const float tv = tao[h];
    const float t2 = tv * tv;
    const float nb = -0.5f / (t2 * t2);
    const float nb2 = nb * L2E;             // negative
    const float sqn = sqrtf(-nb2);
    const float R = sqrtf(-40.0f / nb2) + 1.0f;   // conservative (superset)

    // contiguous chunk range
    int c_lo = (int)floorf(((float)q0 - R) * (1.0f / 64.0f));
    int c_hi = (int)floorf(((float)(q0 + 63) + R) * (1.0f / 64.0f));
    if (c_lo < 0) c_lo = 0;
    if (c_hi > (LQ / 64 - 1)) c_hi = LQ / 64 - 1;
    if (c_hi < c_lo) c_hi = c_lo;

    // staging lane mapping: inst covers 8 rows x 8 swizzled 16B chunks
    const int lr = lane >> 3;        // 0..7
    const int sch = (lane & 7) ^ lr; // XOR-swizzled source chunk
    const u16* kS0 = Kbase + (size_t)(16 * w + lr) * DH + 8 * sch;
    const u16* kS1 = Kbase + (size_t)(16 * w + 8 + lr) * DH + 8 * sch;
    const u16* vS0 = Vtbase + (size_t)(16 * w + lr) * LQ + 8 * sch;
    const u16* vS1 = Vtbase + (size_t)(16 * w + 8 + lr) * LQ + 8 * sch;

    // Q fragments (registers)
    const int qrow = q0 + w * 16 + lane15;
    short8 qB0, qB1;
    {
        const u16* qp_ = Qg + ((size_t)bh * LQ + qrow) * DH + quad * 8;
        qB0 = *(const short8*)(qp_);
        qB1 = *(const short8*)(qp_ + 32);
    }

    const int s0 = (quad ^ (lane15 & 7)) * 8;
    const int s1 = ((4 + quad) ^ (lane15 & 7)) * 8;

    // pre-scaled per-element key offsets: (kt*16+r)*sqn
    float crs[16];
#pragma unroll
    for (int i = 0; i < 16; i++)
        crs[i] = (float)((i >> 2) * 16 + (i & 3)) * sqn;

    // bf16 ones A-fragment for MFMA row-sum
    short8 ones;
#pragma unroll
    for (int i = 0; i < 8; i++) ones[i] = (short)0x3F80;

    f32x4 O[4];
#pragma unroll
    for (int mt = 0; mt < 4; mt++) O[mt] = (f32x4){0,0,0,0};
    f32x4 Lacc = (f32x4){0,0,0,0};

    const float eb0 = (float)(qrow - quad * 4);
    const int prow = w * 16 + lane15;

    // prologue: stage first chunk into buffer 0
    gl_lds16(kS0 + (size_t)c_lo * (64 * DH), &Ks[0][16 * w][0]);
    gl_lds16(kS1 + (size_t)c_lo * (64 * DH), &Ks[0][16 * w + 8][0]);
    gl_lds16(vS0 + 64 * c_lo, &Vt[0][16 * w][0]);
    gl_lds16(vS1 + 64 * c_lo, &Vt[0][16 * w + 8][0]);
    __syncthreads();

    int p = 0;
    for (int c = c_lo; c <= c_hi; ++c) {
        // mask bias regs (quad-uniform, L1-hot) -- issued BEFORE prefetch
        float4 mv[4];
#pragma unroll
        for (int kt = 0; kt < 4; kt++)
            mv[kt] = *(const float4*)(mrow + 64 * c + kt * 16 + quad * 4);

        // prefetch next chunk into other buffer (drains at barrier)
        if (c < c_hi) {
            gl_lds16(kS0 + (size_t)(c + 1) * (64 * DH), &Ks[p ^ 1][16 * w][0]);
            gl_lds16(kS1 + (size_t)(c + 1) * (64 * DH), &Ks[p ^ 1][16 * w + 8][0]);
            gl_lds16(vS0 + 64 * (c + 1), &Vt[p ^ 1][16 * w][0]);
            gl_lds16(vS1 + 64 * (c + 1), &Vt[p ^ 1][16 * w + 8][0]);
        }

        // QK^T: S[kt] = K[16 keys] x Q[16 q] over D=64
        f32x4 S[4];
#pragma unroll
        for (int kt = 0; kt < 4; kt++) {
            const u16* kr = &Ks[p][kt * 16 + lane15][0];
            const short8 ka = *(const short8*)(kr + s0);
            const short8 kb = *(const short8*)(kr + s1);
            S[kt] = __builtin_amdgcn_mfma_f32_16x16x32_bf16(ka, qB0, (f32x4){0,0,0,0}, 0, 0, 0);
            S[kt] = __builtin_amdgcn_mfma_f32_16x16x32_bf16(kb, qB1, S[kt], 0, 0, 0);
        }

        // softmax (fixed max): p = exp2(S*C1 - dp^2 + maskbias)
        const float ebS = (eb0 - (float)(64 * c)) * sqn;
        float lacc_dummy;
        (void)lacc_dummy;
#pragma unroll
        for (int kt = 0; kt < 4; kt++) {
            float pr[4];
#pragma unroll
            for (int r = 0; r < 4; r++) {
                const float dp = ebS - crs[kt * 4 + r];
                const float tb = fmaf(-dp, dp, ((const float*)&mv[kt])[r]);
                pr[r] = fexp2(fmaf(S[kt][r], C1, tb));
            }
            uint2 pk2;
            pk2.x = pkbf(pr[0], pr[1]);
            pk2.y = pkbf(pr[2], pr[3]);
            *(uint2*)&PT[prow][kt * 16 + quad * 4] = pk2;
        }

        // PV + MFMA row-sum of P
        const short8 pB0 = *(const short8*)&PT[prow][quad * 8];
        const short8 pB1 = *(const short8*)&PT[prow][32 + quad * 8];
        Lacc = __builtin_amdgcn_mfma_f32_16x16x32_bf16(ones, pB0, Lacc, 0, 0, 0);
        Lacc = __builtin_amdgcn_mfma_f32_16x16x32_bf16(ones, pB1, Lacc, 0, 0, 0);
#pragma unroll
        for (int mt = 0; mt < 4; mt++) {
            const u16* vr = &Vt[p][mt * 16 + lane15][0];
            const short8 va = *(const short8*)(vr + s0);
            const short8 vb = *(const short8*)(vr + s1);
            O[mt] = __builtin_amdgcn_mfma_f32_16x16x32_bf16(va, pB0, O[mt], 0, 0, 0);
            O[mt] = __builtin_amdgcn_mfma_f32_16x16x32_bf16(vb, pB1, O[mt], 0, 0, 0);
        }

        __syncthreads();
        p ^= 1;
    }

    {
        const float inv = 1.0f / Lacc[0];   // all 4 acc rows equal the row-sum
        u16* dst = Xa + ((size_t)qrow * BQ + b) * HID + h * DH;
#pragma unroll
        for (int mt = 0; mt < 4; mt++) {
            uint2 pk2;
            pk2.x = pkbf(O[mt][0] * inv, O[mt][1] * inv);
            pk2.y = pkbf(O[mt][2] * inv, O[mt][3] * inv);
            *(uint2*)(dst + mt * 16 + quad * 4) = pk2;
        }
    }
}

// ---------------------------------------------------------------------------
extern "C" void kernel_launch(void* const* d_in, const int* in_sizes, int n_in,
                              void* d_out, int out_size, void* d_ws, size_t ws_size,
                              hipStream_t stream) {
    const float* q    = (const float*)d_in[0];
    const float* k    = (const float*)d_in[1];
    const float* v    = (const float*)d_in[2];
    const void*  mask = d_in[3];
    const float* wq   = (const float*)d_in[4];
    const float* wk   = (const float*)d_in[5];
    const float* wv   = (const float*)d_in[6];
    const float* wfc  = (const float*)d_in[7];
    const float* bq   = (const float*)d_in[8];
    const float* bk   = (const float*)d_in[9];
    const float* bv   = (const float*)d_in[10];
    const float* bfc  = (const float*)d_in[11];
    const float* tao  = (const float*)d_in[12];

    const size_t NE = (size_t)LQ * BQ * HID;  // 4,194,304
    const size_t NW = (size_t)HID * HID;      // 1,048,576
    u16* base = (u16*)d_ws;
    u16* Qp    = base;            // [bh][l][d]
    u16* Kp    = base + NE;       // [bh][l][d]
    u16* Vtp   = base + 2 * NE;   // [bh][d][l]
    u16* Xa    = base + 3 * NE;
    u16* qbf   = base + 4 * NE;
    u16* kbf   = base + 5 * NE;
    u16* vbf   = base + 6 * NE;
    u16* wqbf  = base + 7 * NE;
    u16* wkbf  = wqbf + NW;
    u16* wvbf  = wkbf + NW;
    u16* wfcbf = wvbf + NW;
    float* maskF = (float*)(wfcbf + NW);

    CastArgs ca;
    ca.s[0] = q;   ca.d[0] = qbf;   ca.n[0] = (int)NE;
    ca.s[1] = k;   ca.d[1] = kbf;   ca.n[1] = (int)NE;
    ca.s[2] = v;   ca.d[2] = vbf;   ca.n[2] = (int)NE;
    ca.s[3] = wq;  ca.d[3] = wqbf;  ca.n[3] = (int)NW;
    ca.s[4] = wk;  ca.d[4] = wkbf;  ca.n[4] = (int)NW;
    ca.s[5] = wv;  ca.d[5] = wvbf;  ca.n[5] = (int)NW;
    ca.s[6] = wfc; ca.d[6] = wfcbf; ca.n[6] = (int)NW;
    ca.mraw = (const unsigned char*)mask;
    ca.mout = maskF;
    ca.mn = BQ * LQ;
    castw<<<dim3(256, 8), 256, 0, stream>>>(ca);

    QkvArgs ga;
    ga.A[0] = qbf;  ga.W[0] = wqbf;  ga.bias[0] = bq;  ga.out[0] = Qp;
    ga.A[1] = kbf;  ga.W[1] = wkbf;  ga.bias[1] = bk;  ga.out[1] = Kp;
    ga.A[2] = vbf;  ga.W[2] = wvbf;  ga.bias[2] = bv;  ga.out[2] = Vtp;
    gemm_qkv<<<dim3(32, 8, 3), 256, 0, stream>>>(ga);

    attn_kernel<<<dim3(32, 32), 256, 0, stream>>>(Qp, Kp, Vtp, maskF, tao, Xa);

    gemm_fc<<<dim3(32, 16), 256, 0, stream>>>(Xa, wfcbf, bfc, (float*)d_out);
}

// Round 4
// 231.525 us; speedup vs baseline: 1.0401x; 1.0216x over previous
//
#include <hip/hip_runtime.h>

// Problem constants
#define LQ   2048
#define BQ   2
#define HID  1024
#define NH   16
#define DH   64
#define SCALE 0.125f
#define L2E  1.44269504088896f
#define C1   0.18033688011f     // SCALE * log2(e)
#define EXPOFF 23.0831206542f   // 16 * log2(e); fixed softmax max M=16
#define MASKNEG (-1024.0f)      // masked-key additive bias

using short8  = __attribute__((ext_vector_type(8))) short;
using ushort8 = __attribute__((ext_vector_type(8))) unsigned short;
using f32x4   = __attribute__((ext_vector_type(4))) float;
typedef unsigned short u16;
typedef __attribute__((ext_vector_type(2))) __bf16 bf16x2;

__device__ inline u16 f2bf(float x) {
    unsigned int u = __float_as_uint(x);
    u = (u + 0x7fffu + ((u >> 16) & 1u)) >> 16;   // RNE
    return (u16)u;
}

#if defined(__has_builtin)
#if __has_builtin(__builtin_amdgcn_cvt_pk_bf16_f32)
#define HAVE_PKBF 1
#endif
#if __has_builtin(__builtin_amdgcn_exp2f)
#define HAVE_EXP2 1
#endif
#endif

__device__ inline unsigned int pkbf(float a, float b) {
#ifdef HAVE_PKBF
    bf16x2 r = __builtin_amdgcn_cvt_pk_bf16_f32(a, b);
    return __builtin_bit_cast(unsigned int, r);
#else
    return (unsigned int)f2bf(a) | ((unsigned int)f2bf(b) << 16);
#endif
}

__device__ inline float fexp2(float x) {
#ifdef HAVE_EXP2
    return __builtin_amdgcn_exp2f(x);
#else
    return exp2f(x);
#endif
}

// async global->LDS, 16B per lane; LDS dest = wave-uniform base + lane*16
__device__ inline void gl_lds16(const void* g, void* l) {
    __builtin_amdgcn_global_load_lds(
        (const __attribute__((address_space(1))) void*)g,
        (__attribute__((address_space(3))) void*)l, 16, 0, 0);
}

// ---------------------------------------------------------------------------
// castw: cast 7 tensors fp32->bf16 (y=0..6) + mask decode (y==7, x==0).
// Mask emits FLOAT additive bias per key: -EXPOFF (keep) or
// MASKNEG-EXPOFF (masked; exp2 underflows to exactly 0).
// ---------------------------------------------------------------------------
struct CastArgs {
    const float* s[7];
    u16* d[7];
    int n[7];
    const unsigned char* mraw;
    float* mout;
    int mn;
};

__global__ __launch_bounds__(256) void castw(CastArgs a) {
    const int y = blockIdx.y;
    const int t = threadIdx.x;
    if (y == 7) {
        if (blockIdx.x != 0) return;
        __shared__ int cnt;
        if (t == 0) cnt = 0;
        __syncthreads();
        int local = 0;
        for (int i = t; i < a.mn; i += 256)
            if ((i & 3) && a.mraw[i]) local++;
        atomicAdd(&cnt, local);
        __syncthreads();
        bool isInt32 = (cnt == 0);
        const int* mi = (const int*)a.mraw;
        for (int i = t; i < a.mn; i += 256) {
            const bool m = isInt32 ? (mi[i] != 0) : (a.mraw[i] != 0);
            a.mout[i] = m ? (MASKNEG - EXPOFF) : (-EXPOFF);
        }
        return;
    }
    const float* s = a.s[y];
    u16* d = a.d[y];
    const int n4 = a.n[y] >> 2;
    for (int i = blockIdx.x * 256 + t; i < n4; i += gridDim.x * 256) {
        float4 v = *(const float4*)(s + (size_t)i * 4);
        uint2 p;
        p.x = pkbf(v.x, v.y);
        p.y = pkbf(v.z, v.w);
        *(uint2*)(d + (size_t)i * 4) = p;
    }
}

// ---------------------------------------------------------------------------
// Batched QKV MFMA bf16 GEMM, BK=64, tile 128x128, 256 thr.
// DOUBLE-BUFFERED LDS + single barrier per K-step (2-phase prefetch).
// LDS [2][128][64] unpadded, XOR swizzle: 16B chunk c of row r at slot c^(r&7).
// z=0,1: write bf16 [bh][l][d]. z=2: write bf16 V^T [bh][d][l].
// ---------------------------------------------------------------------------
struct QkvArgs {
    const u16* A[3];
    const u16* W[3];
    const float* bias[3];
    u16* out[3];
};

__global__ __launch_bounds__(256) void gemm_qkv(QkvArgs ga) {
    __shared__ u16 As[2][128][64];
    __shared__ u16 Bs[2][128][64];

    const int z = blockIdx.z;
    const u16* A = ga.A[z];
    const u16* W = ga.W[z];
    const float* bias = ga.bias[z];
    u16* outp = ga.out[z];

    const int t = threadIdx.x;
    const int m0 = blockIdx.x * 128;
    const int n0 = blockIdx.y * 128;
    const int lane = t & 63;
    const int lane15 = lane & 15;
    const int quad = lane >> 4;
    const int w = t >> 6;
    const int wm = (w >> 1) * 64;
    const int wn = (w & 1) * 64;

    const int lrow = lane >> 3;                     // 0..7
    const int ch = (lane & 7) ^ ((lane >> 3) & 7);  // source chunk
    const u16* aS = A + (size_t)(m0 + 32 * w + lrow) * HID + 8 * ch;
    const u16* bS = W + (size_t)(n0 + 32 * w + lrow) * HID + 8 * ch;

    const int s0 = (quad ^ (lane15 & 7)) * 8;
    const int s1 = ((4 + quad) ^ (lane15 & 7)) * 8;

    f32x4 acc[4][4];
#pragma unroll
    for (int i = 0; i < 4; i++)
#pragma unroll
        for (int j = 0; j < 4; j++) acc[i][j] = (f32x4){0,0,0,0};

    // prologue: stage tile 0 into buffer 0
#pragma unroll
    for (int i = 0; i < 4; i++) {
        gl_lds16(aS + (size_t)(8 * i) * HID, &As[0][32 * w + 8 * i][0]);
        gl_lds16(bS + (size_t)(8 * i) * HID, &Bs[0][32 * w + 8 * i][0]);
    }
    __syncthreads();

    int p = 0;
    for (int k0 = 0; k0 < HID; k0 += 64) {
        short8 af0[4], af1[4], bf0[4], bf1[4];
#pragma unroll
        for (int i = 0; i < 4; i++) {
            const u16* ar = &As[p][wm + i * 16 + lane15][0];
            const u16* br = &Bs[p][wn + i * 16 + lane15][0];
            af0[i] = *(const short8*)(ar + s0);
            af1[i] = *(const short8*)(ar + s1);
            bf0[i] = *(const short8*)(br + s0);
            bf1[i] = *(const short8*)(br + s1);
        }
        if (k0 + 64 < HID) {
#pragma unroll
            for (int i = 0; i < 4; i++) {
                gl_lds16(aS + (size_t)(8 * i) * HID + (k0 + 64), &As[p ^ 1][32 * w + 8 * i][0]);
                gl_lds16(bS + (size_t)(8 * i) * HID + (k0 + 64), &Bs[p ^ 1][32 * w + 8 * i][0]);
            }
        }
#pragma unroll
        for (int mi = 0; mi < 4; mi++)
#pragma unroll
            for (int ni = 0; ni < 4; ni++) {
                acc[mi][ni] = __builtin_amdgcn_mfma_f32_16x16x32_bf16(af0[mi], bf0[ni], acc[mi][ni], 0, 0, 0);
                acc[mi][ni] = __builtin_amdgcn_mfma_f32_16x16x32_bf16(af1[mi], bf1[ni], acc[mi][ni], 0, 0, 0);
            }
        __syncthreads();
        p ^= 1;
    }

#pragma unroll
    for (int mi = 0; mi < 4; mi++) {
#pragma unroll
        for (int ni = 0; ni < 4; ni++) {
            const int n = n0 + wn + ni * 16 + lane15;
            const float bv = bias[n];
            const int h = n >> 6, d = n & 63;
#pragma unroll
            for (int r = 0; r < 4; r++) {
                const int m = m0 + wm + mi * 16 + quad * 4 + r;
                const float c = acc[mi][ni][r] + bv;
                const int b = m & 1, l = m >> 1;
                if (z < 2) {
                    outp[(((size_t)(b * NH + h)) * LQ + l) * DH + d] = f2bf(c);
                } else {
                    outp[(((size_t)(b * NH + h)) * DH + d) * LQ + l] = f2bf(c);
                }
            }
        }
    }
}

// ---------------------------------------------------------------------------
// FC GEMM (fp32 out), 128x64 tile, BK=64, double-buffered 2-phase.
// ---------------------------------------------------------------------------
__global__ __launch_bounds__(256) void gemm_fc(const u16* __restrict__ A,
                                               const u16* __restrict__ W,
                                               const float* __restrict__ bias,
                                               float* __restrict__ outp) {
    __shared__ u16 As[2][128][64];
    __shared__ u16 Bs[2][64][64];

    const int t = threadIdx.x;
    const int m0 = blockIdx.x * 128;
    const int n0 = blockIdx.y * 64;
    const int lane = t & 63;
    const int lane15 = lane & 15;
    const int quad = lane >> 4;
    const int w = t >> 6;
    const int wm = (w >> 1) * 64;
    const int wn = (w & 1) * 32;

    const int lrow = lane >> 3;
    const int ch = (lane & 7) ^ ((lane >> 3) & 7);
    const u16* aS = A + (size_t)(m0 + 32 * w + lrow) * HID + 8 * ch;
    const u16* bS = W + (size_t)(n0 + 16 * w + lrow) * HID + 8 * ch;

    const int s0 = (quad ^ (lane15 & 7)) * 8;
    const int s1 = ((4 + quad) ^ (lane15 & 7)) * 8;

    f32x4 acc[4][2];
#pragma unroll
    for (int i = 0; i < 4; i++)
#pragma unroll
        for (int j = 0; j < 2; j++) acc[i][j] = (f32x4){0,0,0,0};

#pragma unroll
    for (int i = 0; i < 4; i++)
        gl_lds16(aS + (size_t)(8 * i) * HID, &As[0][32 * w + 8 * i][0]);
#pragma unroll
    for (int i = 0; i < 2; i++)
        gl_lds16(bS + (size_t)(8 * i) * HID, &Bs[0][16 * w + 8 * i][0]);
    __syncthreads();

    int p = 0;
    for (int k0 = 0; k0 < HID; k0 += 64) {
        short8 af0[4], af1[4], bf0[2], bf1[2];
#pragma unroll
        for (int i = 0; i < 4; i++) {
            const u16* ar = &As[p][wm + i * 16 + lane15][0];
            af0[i] = *(const short8*)(ar + s0);
            af1[i] = *(const short8*)(ar + s1);
        }
#pragma unroll
        for (int j = 0; j < 2; j++) {
            const u16* br = &Bs[p][wn + j * 16 + lane15][0];
            bf0[j] = *(const short8*)(br + s0);
            bf1[j] = *(const short8*)(br + s1);
        }
        if (k0 + 64 < HID) {
#pragma unroll
            for (int i = 0; i < 4; i++)
                gl_lds16(aS + (size_t)(8 * i) * HID + (k0 + 64), &As[p ^ 1][32 * w + 8 * i][0]);
#pragma unroll
            for (int i = 0; i < 2; i++)
                gl_lds16(bS + (size_t)(8 * i) * HID + (k0 + 64), &Bs[p ^ 1][16 * w + 8 * i][0]);
        }
#pragma unroll
        for (int mi = 0; mi < 4; mi++)
#pragma unroll
            for (int ni = 0; ni < 2; ni++) {
                acc[mi][ni] = __builtin_amdgcn_mfma_f32_16x16x32_bf16(af0[mi], bf0[ni], acc[mi][ni], 0, 0, 0);
                acc[mi][ni] = __builtin_amdgcn_mfma_f32_16x16x32_bf16(af1[mi], bf1[ni], acc[mi][ni], 0, 0, 0);
            }
        __syncthreads();
        p ^= 1;
    }

#pragma unroll
    for (int mi = 0; mi < 4; mi++) {
#pragma unroll
        for (int ni = 0; ni < 2; ni++) {
            const int n = n0 + wn + ni * 16 + lane15;
            const float bv = bias[n];
#pragma unroll
            for (int r = 0; r < 4; r++) {
                const int m = m0 + wm + mi * 16 + quad * 4 + r;
                outp[(size_t)m * HID + n] = acc[mi][ni][r] + bv;
            }
        }
    }
}

// ---------------------------------------------------------------------------
// MFMA bf16 flash attention v5 (LDS-BW-bound fix):
//  - q-tile 128, 4 waves, each wave owns 32 q rows (two 16-row halves).
//    K/V LDS fragments are read ONCE per wave per chunk and reused in
//    registers for both halves -> LDS read bytes per S-element HALVED.
//  - grid 32x16 = 512 blocks = 2/CU; __launch_bounds__(256,2) frees the
//    full 256-VGPR budget (occupancy is grid-capped anyway).
//  - 64-key chunks, K/V double-buffered, 1 barrier/chunk, prefetch c+1.
//  - mask bias from global (quad-broadcast), row-sum l via ones-MFMA.
// ---------------------------------------------------------------------------
#define PSTR 72

__global__ __launch_bounds__(256, 2) void attn_kernel(const u16* __restrict__ Qg,
                                                      const u16* __restrict__ Kg,
                                                      const u16* __restrict__ Vtg,
                                                      const float* __restrict__ maskF,
                                                      const float* __restrict__ tao,
                                                      u16* __restrict__ Xa) {
    __shared__ u16 Ks[2][64][64];   // [buf][key][d], chunk c of row r at slot c^(r&7)
    __shared__ u16 Vt[2][64][64];   // [buf][d][key], same swizzle
    __shared__ u16 PT[128][PSTR];   // wave-private rows (wave w owns rows 32w..32w+31)

    const int bh = blockIdx.x;
    const int q0 = blockIdx.y * 128;
    const int b = bh >> 4;
    const int h = bh & 15;
    const int t = threadIdx.x;
    const int w = t >> 6;            // wave 0..3
    const int lane = t & 63;
    const int lane15 = lane & 15;
    const int quad = lane >> 4;

    const u16* Kbase = Kg + (size_t)bh * LQ * DH;
    const u16* Vtbase = Vtg + (size_t)bh * DH * LQ;
    const float* mrow = maskF + b * LQ;

    const float tv = tao[h];
    const float t2 = tv * tv;
    const float nb = -0.5f / (t2 * t2);
    const float nb2 = nb * L2E;             // negative
    const float sqn = sqrtf(-nb2);
    const float R = sqrtf(-40.0f / nb2) + 1.0f;   // conservative (superset)

    // contiguous chunk range covering q0..q0+127
    int c_lo = (int)floorf(((float)q0 - R) * (1.0f / 64.0f));
    int c_hi = (int)floorf(((float)(q0 + 127) + R) * (1.0f / 64.0f));
    if (c_lo < 0) c_lo = 0;
    if (c_hi > (LQ / 64 - 1)) c_hi = LQ / 64 - 1;
    if (c_hi < c_lo) c_hi = c_lo;

    // staging lane mapping: inst covers 8 rows x 8 swizzled 16B chunks
    const int lr = lane >> 3;        // 0..7
    const int sch = (lane & 7) ^ lr; // XOR-swizzled source chunk
    const u16* kS0 = Kbase + (size_t)(16 * w + lr) * DH + 8 * sch;
    const u16* kS1 = Kbase + (size_t)(16 * w + 8 + lr) * DH + 8 * sch;
    const u16* vS0 = Vtbase + (size_t)(16 * w + lr) * LQ + 8 * sch;
    const u16* vS1 = Vtbase + (size_t)(16 * w + 8 + lr) * LQ + 8 * sch;

    // Q fragments (registers), two 16-row halves per wave
    const int qrow0 = q0 + w * 32 + lane15;
    const int qrow1 = qrow0 + 16;
    short8 qA00, qA01, qA10, qA11;
    {
        const u16* qp0 = Qg + ((size_t)bh * LQ + qrow0) * DH + quad * 8;
        qA00 = *(const short8*)(qp0);
        qA01 = *(const short8*)(qp0 + 32);
        const u16* qp1 = Qg + ((size_t)bh * LQ + qrow1) * DH + quad * 8;
        qA10 = *(const short8*)(qp1);
        qA11 = *(const short8*)(qp1 + 32);
    }

    const int s0 = (quad ^ (lane15 & 7)) * 8;
    const int s1 = ((4 + quad) ^ (lane15 & 7)) * 8;

    // pre-scaled per-element key offsets: (kt*16+r)*sqn
    float crs[16];
#pragma unroll
    for (int i = 0; i < 16; i++)
        crs[i] = (float)((i >> 2) * 16 + (i & 3)) * sqn;

    // bf16 ones A-fragment for MFMA row-sum
    short8 ones;
#pragma unroll
    for (int i = 0; i < 8; i++) ones[i] = (short)0x3F80;

    f32x4 O0[4], O1[4];
#pragma unroll
    for (int mt = 0; mt < 4; mt++) { O0[mt] = (f32x4){0,0,0,0}; O1[mt] = (f32x4){0,0,0,0}; }
    f32x4 Lac0 = (f32x4){0,0,0,0};
    f32x4 Lac1 = (f32x4){0,0,0,0};

    const float eb00 = (float)(qrow0 - quad * 4);
    const float eb01 = (float)(qrow1 - quad * 4);
    const int prow0 = w * 32 + lane15;
    const int prow1 = prow0 + 16;

    // prologue: stage first chunk into buffer 0
    gl_lds16(kS0 + (size_t)c_lo * (64 * DH), &Ks[0][16 * w][0]);
    gl_lds16(kS1 + (size_t)c_lo * (64 * DH), &Ks[0][16 * w + 8][0]);
    gl_lds16(vS0 + 64 * c_lo, &Vt[0][16 * w][0]);
    gl_lds16(vS1 + 64 * c_lo, &Vt[0][16 * w + 8][0]);
    __syncthreads();

    int p = 0;
    for (int c = c_lo; c <= c_hi; ++c) {
        // mask bias regs (quad-uniform, L1-hot) -- issued BEFORE prefetch
        float4 mv[4];
#pragma unroll
        for (int kt = 0; kt < 4; kt++)
            mv[kt] = *(const float4*)(mrow + 64 * c + kt * 16 + quad * 4);

        // prefetch next chunk into other buffer (drains at barrier)
        if (c < c_hi) {
            gl_lds16(kS0 + (size_t)(c + 1) * (64 * DH), &Ks[p ^ 1][16 * w][0]);
            gl_lds16(kS1 + (size_t)(c + 1) * (64 * DH), &Ks[p ^ 1][16 * w + 8][0]);
            gl_lds16(vS0 + 64 * (c + 1), &Vt[p ^ 1][16 * w][0]);
            gl_lds16(vS1 + 64 * (c + 1), &Vt[p ^ 1][16 * w + 8][0]);
        }

        // QK^T for BOTH halves; K frags read once, reused from registers
        f32x4 S0[4], S1[4];
#pragma unroll
        for (int kt = 0; kt < 4; kt++) {
            const u16* kr = &Ks[p][kt * 16 + lane15][0];
            const short8 ka = *(const short8*)(kr + s0);
            const short8 kb = *(const short8*)(kr + s1);
            S0[kt] = __builtin_amdgcn_mfma_f32_16x16x32_bf16(ka, qA00, (f32x4){0,0,0,0}, 0, 0, 0);
            S0[kt] = __builtin_amdgcn_mfma_f32_16x16x32_bf16(kb, qA01, S0[kt], 0, 0, 0);
            S1[kt] = __builtin_amdgcn_mfma_f32_16x16x32_bf16(ka, qA10, (f32x4){0,0,0,0}, 0, 0, 0);
            S1[kt] = __builtin_amdgcn_mfma_f32_16x16x32_bf16(kb, qA11, S1[kt], 0, 0, 0);
        }

        // softmax (fixed max): p = exp2(S*C1 - dp^2 + maskbias), both halves
        const float ebS0 = (eb00 - (float)(64 * c)) * sqn;
        const float ebS1 = (eb01 - (float)(64 * c)) * sqn;
#pragma unroll
        for (int kt = 0; kt < 4; kt++) {
            float pr0[4], pr1[4];
#pragma unroll
            for (int r = 0; r < 4; r++) {
                const float mb = ((const float*)&mv[kt])[r];
                const float dp0 = ebS0 - crs[kt * 4 + r];
                const float dp1 = ebS1 - crs[kt * 4 + r];
                pr0[r] = fexp2(fmaf(S0[kt][r], C1, fmaf(-dp0, dp0, mb)));
                pr1[r] = fexp2(fmaf(S1[kt][r], C1, fmaf(-dp1, dp1, mb)));
            }
            uint2 pk0, pk1;
            pk0.x = pkbf(pr0[0], pr0[1]);
            pk0.y = pkbf(pr0[2], pr0[3]);
            pk1.x = pkbf(pr1[0], pr1[1]);
            pk1.y = pkbf(pr1[2], pr1[3]);
            *(uint2*)&PT[prow0][kt * 16 + quad * 4] = pk0;
            *(uint2*)&PT[prow1][kt * 16 + quad * 4] = pk1;
        }

        // P fragments + MFMA row-sums
        const short8 pB00 = *(const short8*)&PT[prow0][quad * 8];
        const short8 pB01 = *(const short8*)&PT[prow0][32 + quad * 8];
        const short8 pB10 = *(const short8*)&PT[prow1][quad * 8];
        const short8 pB11 = *(const short8*)&PT[prow1][32 + quad * 8];
        Lac0 = __builtin_amdgcn_mfma_f32_16x16x32_bf16(ones, pB00, Lac0, 0, 0, 0);
        Lac0 = __builtin_amdgcn_mfma_f32_16x16x32_bf16(ones, pB01, Lac0, 0, 0, 0);
        Lac1 = __builtin_amdgcn_mfma_f32_16x16x32_bf16(ones, pB10, Lac1, 0, 0, 0);
        Lac1 = __builtin_amdgcn_mfma_f32_16x16x32_bf16(ones, pB11, Lac1, 0, 0, 0);

        // PV for BOTH halves; V frags read once, reused from registers
#pragma unroll
        for (int mt = 0; mt < 4; mt++) {
            const u16* vr = &Vt[p][mt * 16 + lane15][0];
            const short8 va = *(const short8*)(vr + s0);
            const short8 vb = *(const short8*)(vr + s1);
            O0[mt] = __builtin_amdgcn_mfma_f32_16x16x32_bf16(va, pB00, O0[mt], 0, 0, 0);
            O0[mt] = __builtin_amdgcn_mfma_f32_16x16x32_bf16(vb, pB01, O0[mt], 0, 0, 0);
            O1[mt] = __builtin_amdgcn_mfma_f32_16x16x32_bf16(va, pB10, O1[mt], 0, 0, 0);
            O1[mt] = __builtin_amdgcn_mfma_f32_16x16x32_bf16(vb, pB11, O1[mt], 0, 0, 0);
        }

        __syncthreads();
        p ^= 1;
    }

    {
        const float inv0 = 1.0f / Lac0[0];
        u16* dst0 = Xa + ((size_t)qrow0 * BQ + b) * HID + h * DH;
#pragma unroll
        for (int mt = 0; mt < 4; mt++) {
            uint2 pk2;
            pk2.x = pkbf(O0[mt][0] * inv0, O0[mt][1] * inv0);
            pk2.y = pkbf(O0[mt][2] * inv0, O0[mt][3] * inv0);
            *(uint2*)(dst0 + mt * 16 + quad * 4) = pk2;
        }
        const float inv1 = 1.0f / Lac1[0];
        u16* dst1 = Xa + ((size_t)qrow1 * BQ + b) * HID + h * DH;
#pragma unroll
        for (int mt = 0; mt < 4; mt++) {
            uint2 pk2;
            pk2.x = pkbf(O1[mt][0] * inv1, O1[mt][1] * inv1);
            pk2.y = pkbf(O1[mt][2] * inv1, O1[mt][3] * inv1);
            *(uint2*)(dst1 + mt * 16 + quad * 4) = pk2;
        }
    }
}

// ---------------------------------------------------------------------------
extern "C" void kernel_launch(void* const* d_in, const int* in_sizes, int n_in,
                              void* d_out, int out_size, void* d_ws, size_t ws_size,
                              hipStream_t stream) {
    const float* q    = (const float*)d_in[0];
    const float* k    = (const float*)d_in[1];
    const float* v    = (const float*)d_in[2];
    const void*  mask = d_in[3];
    const float* wq   = (const float*)d_in[4];
    const float* wk   = (const float*)d_in[5];
    const float* wv   = (const float*)d_in[6];
    const float* wfc  = (const float*)d_in[7];
    const float* bq   = (const float*)d_in[8];
    const float* bk   = (const float*)d_in[9];
    const float* bv   = (const float*)d_in[10];
    const float* bfc  = (const float*)d_in[11];
    const float* tao  = (const float*)d_in[12];

    const size_t NE = (size_t)LQ * BQ * HID;  // 4,194,304
    const size_t NW = (size_t)HID * HID;      // 1,048,576
    u16* base = (u16*)d_ws;
    u16* Qp    = base;            // [bh][l][d]
    u16* Kp    = base + NE;       // [bh][l][d]
    u16* Vtp   = base + 2 * NE;   // [bh][d][l]
    u16* Xa    = base + 3 * NE;
    u16* qbf   = base + 4 * NE;
    u16* kbf   = base + 5 * NE;
    u16* vbf   = base + 6 * NE;
    u16* wqbf  = base + 7 * NE;
    u16* wkbf  = wqbf + NW;
    u16* wvbf  = wkbf + NW;
    u16* wfcbf = wvbf + NW;
    float* maskF = (float*)(wfcbf + NW);

    CastArgs ca;
    ca.s[0] = q;   ca.d[0] = qbf;   ca.n[0] = (int)NE;
    ca.s[1] = k;   ca.d[1] = kbf;   ca.n[1] = (int)NE;
    ca.s[2] = v;   ca.d[2] = vbf;   ca.n[2] = (int)NE;
    ca.s[3] = wq;  ca.d[3] = wqbf;  ca.n[3] = (int)NW;
    ca.s[4] = wk;  ca.d[4] = wkbf;  ca.n[4] = (int)NW;
    ca.s[5] = wv;  ca.d[5] = wvbf;  ca.n[5] = (int)NW;
    ca.s[6] = wfc; ca.d[6] = wfcbf; ca.n[6] = (int)NW;
    ca.mraw = (const unsigned char*)mask;
    ca.mout = maskF;
    ca.mn = BQ * LQ;
    castw<<<dim3(256, 8), 256, 0, stream>>>(ca);

    QkvArgs ga;
    ga.A[0] = qbf;  ga.W[0] = wqbf;  ga.bias[0] = bq;  ga.out[0] = Qp;
    ga.A[1] = kbf;  ga.W[1] = wkbf;  ga.bias[1] = bk;  ga.out[1] = Kp;
    ga.A[2] = vbf;  ga.W[2] = wvbf;  ga.bias[2] = bv;  ga.out[2] = Vtp;
    gemm_qkv<<<dim3(32, 8, 3), 256, 0, stream>>>(ga);

    attn_kernel<<<dim3(32, 16), 256, 0, stream>>>(Qp, Kp, Vtp, maskF, tao, Xa);

    gemm_fc<<<dim3(32, 16), 256, 0, stream>>>(Xa, wfcbf, bfc, (float*)d_out);
}